// Round 4
// baseline (775.417 us; speedup 1.0000x reference)
//
#include <hip/hip_runtime.h>
#include <math.h>

#define N_ATOMS   131072
#define FEAT      256
#define UNITS     256
#define NSTRUCT   4096
#define ZDIM      1024   // 4*UNITS
#define QDIM      512    // 2*UNITS

__device__ __forceinline__ float sigm(float v) { return 1.0f / (1.0f + __expf(-v)); }

// ---------------------------------------------------------------------------
// Segment offsets: offs[s] = lower_bound(segment_ids, s), s in [0, NSTRUCT]
// ---------------------------------------------------------------------------
__global__ void seg_offs_kernel(const int* __restrict__ seg, int* __restrict__ offs) {
    int s = blockIdx.x * blockDim.x + threadIdx.x;
    if (s > NSTRUCT) return;
    int lo = 0, hi = N_ATOMS;
    while (lo < hi) {
        int mid = (lo + hi) >> 1;
        if (seg[mid] < s) lo = mid + 1; else hi = mid;
    }
    offs[s] = lo;
}

// ---------------------------------------------------------------------------
// GEMM: C[M,N] = A[M,K] @ B[K,N] + bias[N]   (f32, 64x64 tile, 4x4 microtile)
// ---------------------------------------------------------------------------
__global__ __launch_bounds__(256) void gemm_x_kernel(
    const float* __restrict__ A, const float* __restrict__ B,
    const float* __restrict__ bias, float* __restrict__ C,
    int M, int N, int K)
{
    __shared__ float As[32][68];  // [k][m], pad 68 keeps float4 reads 16B-aligned
    __shared__ float Bs[32][64];  // [k][n]

    const int bm = blockIdx.x * 64;
    const int bn = blockIdx.y * 64;
    const int tid = threadIdx.x;
    const int tr = tid >> 4;      // 0..15 -> rows tr*4..tr*4+3
    const int tc = tid & 15;      // 0..15 -> cols tc*4..tc*4+3

    float acc[4][4] = {};

    for (int k0 = 0; k0 < K; k0 += 32) {
        {   // A tile: 64 rows x 32 k, store transposed As[k][m]
            const int kk = tid & 31, r0 = tid >> 5;
            #pragma unroll
            for (int i = 0; i < 8; ++i) {
                int r = r0 + i * 8;
                As[kk][r] = A[(size_t)(bm + r) * K + k0 + kk];
            }
        }
        {   // B tile: 32 k x 64 cols
            const int col = tid & 63, kb = tid >> 6;
            #pragma unroll
            for (int i = 0; i < 8; ++i) {
                int kk = kb + i * 4;
                Bs[kk][col] = B[(size_t)(k0 + kk) * N + bn + col];
            }
        }
        __syncthreads();
        #pragma unroll
        for (int kk = 0; kk < 32; ++kk) {
            const float4 a4 = *(const float4*)&As[kk][tr * 4];
            const float4 b4 = *(const float4*)&Bs[kk][tc * 4];
            const float a_[4] = {a4.x, a4.y, a4.z, a4.w};
            const float b_[4] = {b4.x, b4.y, b4.z, b4.w};
            #pragma unroll
            for (int i = 0; i < 4; ++i)
                #pragma unroll
                for (int j = 0; j < 4; ++j)
                    acc[i][j] = fmaf(a_[i], b_[j], acc[i][j]);
        }
        __syncthreads();
    }

    #pragma unroll
    for (int i = 0; i < 4; ++i) {
        float4 o;
        o.x = acc[i][0] + bias[bn + tc * 4 + 0];
        o.y = acc[i][1] + bias[bn + tc * 4 + 1];
        o.z = acc[i][2] + bias[bn + tc * 4 + 2];
        o.w = acc[i][3] + bias[bn + tc * 4 + 3];
        *(float4*)&C[(size_t)(bm + tr * 4 + i) * N + bn + tc * 4] = o;
    }
}

// ---------------------------------------------------------------------------
// LSTM z-GEMM: z[4096,1024] = [qstar | h] @ [Wk ; Wr] + b
// A = concat(qstar[4096,512], h[4096,256]) along K; K=768
// ---------------------------------------------------------------------------
__global__ __launch_bounds__(256) void lstm_gemm_kernel(
    const float* __restrict__ qstar, const float* __restrict__ h,
    const float* __restrict__ Wk, const float* __restrict__ Wr,
    const float* __restrict__ b, float* __restrict__ z)
{
    __shared__ float As[32][68];
    __shared__ float Bs[32][64];

    const int bm = blockIdx.x * 64;   // rows (structures)
    const int bn = blockIdx.y * 64;   // cols (of 1024)
    const int tid = threadIdx.x;
    const int tr = tid >> 4, tc = tid & 15;

    float acc[4][4] = {};

    for (int k0 = 0; k0 < 768; k0 += 32) {
        {   // A tile (each 32-chunk comes fully from one source: 512 % 32 == 0)
            const int kk = tid & 31, r0 = tid >> 5;
            const int kg = k0 + kk;
            #pragma unroll
            for (int i = 0; i < 8; ++i) {
                int r = r0 + i * 8;
                float v;
                if (kg < 512) v = qstar[(size_t)(bm + r) * QDIM + kg];
                else          v = h[(size_t)(bm + r) * UNITS + (kg - 512)];
                As[kk][r] = v;
            }
        }
        {   // B tile
            const int col = tid & 63, kb = tid >> 6;
            #pragma unroll
            for (int i = 0; i < 8; ++i) {
                int kg = k0 + kb + i * 4;
                float v;
                if (kg < 512) v = Wk[(size_t)kg * ZDIM + bn + col];
                else          v = Wr[(size_t)(kg - 512) * ZDIM + bn + col];
                Bs[kb + i * 4][col] = v;
            }
        }
        __syncthreads();
        #pragma unroll
        for (int kk = 0; kk < 32; ++kk) {
            const float4 a4 = *(const float4*)&As[kk][tr * 4];
            const float4 b4 = *(const float4*)&Bs[kk][tc * 4];
            const float a_[4] = {a4.x, a4.y, a4.z, a4.w};
            const float b_[4] = {b4.x, b4.y, b4.z, b4.w};
            #pragma unroll
            for (int i = 0; i < 4; ++i)
                #pragma unroll
                for (int j = 0; j < 4; ++j)
                    acc[i][j] = fmaf(a_[i], b_[j], acc[i][j]);
        }
        __syncthreads();
    }

    #pragma unroll
    for (int i = 0; i < 4; ++i) {
        float4 o;
        o.x = acc[i][0] + b[bn + tc * 4 + 0];
        o.y = acc[i][1] + b[bn + tc * 4 + 1];
        o.z = acc[i][2] + b[bn + tc * 4 + 2];
        o.w = acc[i][3] + b[bn + tc * 4 + 3];
        *(float4*)&z[(size_t)(bm + tr * 4 + i) * ZDIM + bn + tc * 4] = o;
    }
}

// ---------------------------------------------------------------------------
// Gates: h,c <- lstm gates(z, c).  Keras order i,f,g,o.
// ---------------------------------------------------------------------------
__global__ __launch_bounds__(256) void gates_kernel(
    const float* __restrict__ z, const float* __restrict__ c_in,
    float* __restrict__ h_out, float* __restrict__ c_out)
{
    int idx = blockIdx.x * 256 + threadIdx.x;     // 4096*256
    int s = idx >> 8, ch = idx & 255;
    const float* zr = z + (size_t)s * ZDIM;
    float zi = zr[ch], zf = zr[256 + ch], zg = zr[512 + ch], zo = zr[768 + ch];
    float cold = c_in[idx];
    float cn = sigm(zf) * cold + sigm(zi) * tanhf(zg);
    float hn = sigm(zo) * tanhf(cn);
    h_out[idx] = hn;
    c_out[idx] = cn;
}

// Step-1 closed form: q*=0, h=0, c=0 -> z = b (same for every structure)
__global__ void h1c1_kernel(const float* __restrict__ b, float* __restrict__ hc_rows) {
    int ch = threadIdx.x;
    float zi = b[ch], zg = b[512 + ch], zo = b[768 + ch];
    float cn = sigm(zi) * tanhf(zg);          // c_old = 0
    float hn = sigm(zo) * tanhf(cn);
    hc_rows[ch] = hn;
    hc_rows[256 + ch] = cn;
}

__global__ __launch_bounds__(256) void bcast_kernel(
    const float* __restrict__ hc_rows, float* __restrict__ h, float* __restrict__ c)
{
    int idx = blockIdx.x * 256 + threadIdx.x;
    int ch = idx & 255;
    h[idx] = hc_rows[ch];
    c[idx] = hc_rows[256 + ch];
}

// ---------------------------------------------------------------------------
// Attention: one block per segment, thread = channel, online softmax.
// Writes q_star[s] = [qt | rt].
// ---------------------------------------------------------------------------
__global__ __launch_bounds__(256) void attn_kernel(
    const float* __restrict__ x, const float* __restrict__ h,
    const int* __restrict__ offs, float* __restrict__ qstar_out)
{
    const int s = blockIdx.x;
    const int ch = threadIdx.x;
    const float q = h[(size_t)s * UNITS + ch];
    const int a0 = offs[s], a1 = offs[s + 1];

    float m = -INFINITY, ssum = 0.0f, r = 0.0f;
    #pragma unroll 4
    for (int a = a0; a < a1; ++a) {
        float xv = x[(size_t)a * FEAT + ch];
        float e = xv * q;
        float mnew = fmaxf(m, e);
        float scale = __expf(m - mnew);      // exp(-inf)=0 on first iter
        float p = __expf(e - mnew);
        ssum = ssum * scale + p;
        r = r * scale + p * xv;
        m = mnew;
    }
    float rt = (a1 > a0) ? (r / ssum) : 0.0f;
    qstar_out[(size_t)s * QDIM + ch] = q;
    qstar_out[(size_t)s * QDIM + UNITS + ch] = rt;
}

// ---------------------------------------------------------------------------
extern "C" void kernel_launch(void* const* d_in, const int* in_sizes, int n_in,
                              void* d_out, int out_size, void* d_ws, size_t ws_size,
                              hipStream_t stream) {
    const float* field  = (const float*)d_in[0];
    const float* Wd     = (const float*)d_in[1];
    const float* bd     = (const float*)d_in[2];
    const float* Wk     = (const float*)d_in[3];
    const float* Wr     = (const float*)d_in[4];
    const float* b_lstm = (const float*)d_in[5];
    const int*   segids = (const int*)d_in[6];

    float* ws   = (float*)d_ws;
    float* x    = ws;                              // 33554432 f
    float* z    = x + (size_t)N_ATOMS * FEAT;      // 4194304 f
    float* qst  = z + (size_t)NSTRUCT * ZDIM;      // 2097152 f
    float* h    = qst + (size_t)NSTRUCT * QDIM;    // 1048576 f
    float* c    = h + (size_t)NSTRUCT * UNITS;     // 1048576 f
    float* hcr  = c + (size_t)NSTRUCT * UNITS;     // 512 f
    int*   offs = (int*)(hcr + 512);               // 4097 i

    seg_offs_kernel<<<(NSTRUCT + 1 + 255) / 256, 256, 0, stream>>>(segids, offs);

    // x = field @ Wd + bd
    gemm_x_kernel<<<dim3(N_ATOMS / 64, FEAT / 64), 256, 0, stream>>>(
        field, Wd, bd, x, N_ATOMS, FEAT, FEAT);

    // step 1 (closed form LSTM from zero state)
    h1c1_kernel<<<1, 256, 0, stream>>>(b_lstm, hcr);
    bcast_kernel<<<NSTRUCT, 256, 0, stream>>>(hcr, h, c);
    attn_kernel<<<NSTRUCT, 256, 0, stream>>>(x, h, offs, qst);

    // steps 2, 3
    for (int step = 1; step < 3; ++step) {
        lstm_gemm_kernel<<<dim3(NSTRUCT / 64, ZDIM / 64), 256, 0, stream>>>(
            qst, h, Wk, Wr, b_lstm, z);
        gates_kernel<<<NSTRUCT, 256, 0, stream>>>(z, c, h, c);
        float* qdst = (step == 2) ? (float*)d_out : qst;
        attn_kernel<<<NSTRUCT, 256, 0, stream>>>(x, h, offs, qdst);
    }
}

// Round 5
// 441.124 us; speedup vs baseline: 1.7578x; 1.7578x over previous
//
#include <hip/hip_runtime.h>
#include <math.h>

#define N_ATOMS   131072
#define FEAT      256
#define UNITS     256
#define NSTRUCT   4096
#define ZDIM      1024   // 4*UNITS
#define QDIM      512    // 2*UNITS
#define KLSTM     768    // QDIM + UNITS

typedef __attribute__((ext_vector_type(8))) __bf16 bf16x8;
typedef __attribute__((ext_vector_type(4))) float  f32x4;

__device__ __forceinline__ float sigm(float v) { return 1.0f / (1.0f + __expf(-v)); }

__device__ __forceinline__ unsigned short bf16_rne(float v) {
    unsigned int u = __float_as_uint(v);
    u += 0x7fffu + ((u >> 16) & 1u);
    return (unsigned short)(u >> 16);
}
__device__ __forceinline__ float bf16_f32(unsigned short b) {
    return __uint_as_float(((unsigned int)b) << 16);
}
__device__ __forceinline__ bf16x8 frag_ld(const unsigned short* p) {
    uint4 u = *(const uint4*)p;
    bf16x8 r; __builtin_memcpy(&r, &u, 16); return r;
}

// ---------------------------------------------------------------------------
// Segment offsets: offs[s] = lower_bound(segment_ids, s)
// ---------------------------------------------------------------------------
__global__ void seg_offs_kernel(const int* __restrict__ seg, int* __restrict__ offs) {
    int s = blockIdx.x * blockDim.x + threadIdx.x;
    if (s > NSTRUCT) return;
    int lo = 0, hi = N_ATOMS;
    while (lo < hi) {
        int mid = (lo + hi) >> 1;
        if (seg[mid] < s) lo = mid + 1; else hi = mid;
    }
    offs[s] = lo;
}

// ---------------------------------------------------------------------------
// Weight prep: transpose + split f32 -> (hi, lo) bf16.  B^T layout [N][K].
// ---------------------------------------------------------------------------
__global__ __launch_bounds__(256) void prep_wd_kernel(
    const float* __restrict__ Wd, unsigned short* __restrict__ Th,
    unsigned short* __restrict__ Tl)
{
    int t = blockIdx.x * 256 + threadIdx.x;       // 65536 = 256*256
    int k = t >> 8, n = t & 255;
    float v = Wd[t];                              // Wd[k][n]
    unsigned short h = bf16_rne(v);
    unsigned short l = bf16_rne(v - bf16_f32(h));
    Th[n * FEAT + k] = h;
    Tl[n * FEAT + k] = l;
}

__global__ __launch_bounds__(256) void prep_wlstm_kernel(
    const float* __restrict__ Wk, const float* __restrict__ Wr,
    unsigned short* __restrict__ Th, unsigned short* __restrict__ Tl)
{
    int t = blockIdx.x * 256 + threadIdx.x;       // 786432 = 768*1024
    int k = t >> 10, n = t & 1023;
    float v = (k < QDIM) ? Wk[t] : Wr[t - QDIM * ZDIM];
    unsigned short h = bf16_rne(v);
    unsigned short l = bf16_rne(v - bf16_f32(h));
    Th[n * KLSTM + k] = h;
    Tl[n * KLSTM + k] = l;
}

// ---------------------------------------------------------------------------
// x = field @ Wd + bd   via split-bf16 MFMA (3 passes: hh + hl + lh)
// 128x128 tile, BK=32, 4 waves (2x2), per-wave 4x4 16x16 fragments.
// A staged f32->hi/lo in-flight; B^T pre-split bf16 [N][K].
// ---------------------------------------------------------------------------
__global__ __launch_bounds__(256) void gemm_x_mfma(
    const float* __restrict__ A,                  // [131072][256] f32
    const unsigned short* __restrict__ BTh,       // [256][256] bf16 bits
    const unsigned short* __restrict__ BTl,
    const float* __restrict__ bias, float* __restrict__ C)
{
    __shared__ unsigned short Ah[128][32], Al[128][32], Bh[128][32], Bl[128][32];
    const int bn = blockIdx.x * 128;              // n fastest -> A-panel L2 reuse
    const int bm = blockIdx.y * 128;
    const int t  = threadIdx.x;
    const int w  = t >> 6, l = t & 63;
    const int wr = w & 1, wc = w >> 1;
    const int lm = l & 15, koff = (l >> 4) * 8;

    f32x4 acc[4][4] = {};

    for (int k0 = 0; k0 < FEAT; k0 += 32) {
        #pragma unroll
        for (int i = 0; i < 4; ++i) {             // A: 128x32 f32 -> hi/lo
            int flat = t + i * 256;
            int m = flat >> 3, kq = flat & 7;
            const float4 v = *(const float4*)&A[(size_t)(bm + m) * FEAT + k0 + kq * 4];
            unsigned short h0 = bf16_rne(v.x), h1 = bf16_rne(v.y);
            unsigned short h2 = bf16_rne(v.z), h3 = bf16_rne(v.w);
            unsigned short l0 = bf16_rne(v.x - bf16_f32(h0));
            unsigned short l1 = bf16_rne(v.y - bf16_f32(h1));
            unsigned short l2 = bf16_rne(v.z - bf16_f32(h2));
            unsigned short l3 = bf16_rne(v.w - bf16_f32(h3));
            uint2 hw, lw;
            hw.x = (unsigned)h0 | ((unsigned)h1 << 16);
            hw.y = (unsigned)h2 | ((unsigned)h3 << 16);
            lw.x = (unsigned)l0 | ((unsigned)l1 << 16);
            lw.y = (unsigned)l2 | ((unsigned)l3 << 16);
            *(uint2*)&Ah[m][kq * 4] = hw;
            *(uint2*)&Al[m][kq * 4] = lw;
        }
        #pragma unroll
        for (int i = 0; i < 2; ++i) {             // B: copy pre-split bf16
            int flat = t + i * 256;
            int n = flat >> 2, kc = flat & 3;
            *(uint4*)&Bh[n][kc * 8] = *(const uint4*)&BTh[(size_t)(bn + n) * FEAT + k0 + kc * 8];
            *(uint4*)&Bl[n][kc * 8] = *(const uint4*)&BTl[(size_t)(bn + n) * FEAT + k0 + kc * 8];
        }
        __syncthreads();
        bf16x8 ah[4], al[4];
        #pragma unroll
        for (int i = 0; i < 4; ++i) {
            ah[i] = frag_ld(&Ah[wr * 64 + i * 16 + lm][koff]);
            al[i] = frag_ld(&Al[wr * 64 + i * 16 + lm][koff]);
        }
        #pragma unroll
        for (int j = 0; j < 4; ++j) {
            bf16x8 bh = frag_ld(&Bh[wc * 64 + j * 16 + lm][koff]);
            bf16x8 bl = frag_ld(&Bl[wc * 64 + j * 16 + lm][koff]);
            #pragma unroll
            for (int i = 0; i < 4; ++i) {
                acc[i][j] = __builtin_amdgcn_mfma_f32_16x16x32_bf16(ah[i], bh, acc[i][j], 0, 0, 0);
                acc[i][j] = __builtin_amdgcn_mfma_f32_16x16x32_bf16(al[i], bh, acc[i][j], 0, 0, 0);
                acc[i][j] = __builtin_amdgcn_mfma_f32_16x16x32_bf16(ah[i], bl, acc[i][j], 0, 0, 0);
            }
        }
        __syncthreads();
    }

    const int lg4 = (l >> 4) * 4;
    #pragma unroll
    for (int i = 0; i < 4; ++i)
        #pragma unroll
        for (int j = 0; j < 4; ++j) {
            int col  = bn + wc * 64 + j * 16 + lm;
            int row0 = bm + wr * 64 + i * 16 + lg4;
            float bb = bias[col];
            #pragma unroll
            for (int r = 0; r < 4; ++r)
                C[(size_t)(row0 + r) * FEAT + col] = acc[i][j][r] + bb;
        }
}

// ---------------------------------------------------------------------------
// z[4096,1024] = [qstar | h] @ [Wk;Wr] + b  via split-bf16 MFMA. K=768.
// ---------------------------------------------------------------------------
__global__ __launch_bounds__(256) void lstm_gemm_mfma(
    const float* __restrict__ qstar, const float* __restrict__ hsrc,
    const unsigned short* __restrict__ BTh,       // [1024][768]
    const unsigned short* __restrict__ BTl,
    const float* __restrict__ bias, float* __restrict__ z)
{
    __shared__ unsigned short Ah[128][32], Al[128][32], Bh[128][32], Bl[128][32];
    const int bn = blockIdx.x * 128;
    const int bm = blockIdx.y * 128;
    const int t  = threadIdx.x;
    const int w  = t >> 6, l = t & 63;
    const int wr = w & 1, wc = w >> 1;
    const int lm = l & 15, koff = (l >> 4) * 8;

    f32x4 acc[4][4] = {};

    for (int k0 = 0; k0 < KLSTM; k0 += 32) {
        const float* Asrc; int lda, kb;
        if (k0 < QDIM) { Asrc = qstar; lda = QDIM;  kb = k0; }
        else           { Asrc = hsrc;  lda = UNITS; kb = k0 - QDIM; }
        #pragma unroll
        for (int i = 0; i < 4; ++i) {
            int flat = t + i * 256;
            int m = flat >> 3, kq = flat & 7;
            const float4 v = *(const float4*)&Asrc[(size_t)(bm + m) * lda + kb + kq * 4];
            unsigned short h0 = bf16_rne(v.x), h1 = bf16_rne(v.y);
            unsigned short h2 = bf16_rne(v.z), h3 = bf16_rne(v.w);
            unsigned short l0 = bf16_rne(v.x - bf16_f32(h0));
            unsigned short l1 = bf16_rne(v.y - bf16_f32(h1));
            unsigned short l2 = bf16_rne(v.z - bf16_f32(h2));
            unsigned short l3 = bf16_rne(v.w - bf16_f32(h3));
            uint2 hw, lw;
            hw.x = (unsigned)h0 | ((unsigned)h1 << 16);
            hw.y = (unsigned)h2 | ((unsigned)h3 << 16);
            lw.x = (unsigned)l0 | ((unsigned)l1 << 16);
            lw.y = (unsigned)l2 | ((unsigned)l3 << 16);
            *(uint2*)&Ah[m][kq * 4] = hw;
            *(uint2*)&Al[m][kq * 4] = lw;
        }
        #pragma unroll
        for (int i = 0; i < 2; ++i) {
            int flat = t + i * 256;
            int n = flat >> 2, kc = flat & 3;
            *(uint4*)&Bh[n][kc * 8] = *(const uint4*)&BTh[(size_t)(bn + n) * KLSTM + k0 + kc * 8];
            *(uint4*)&Bl[n][kc * 8] = *(const uint4*)&BTl[(size_t)(bn + n) * KLSTM + k0 + kc * 8];
        }
        __syncthreads();
        bf16x8 ah[4], al[4];
        #pragma unroll
        for (int i = 0; i < 4; ++i) {
            ah[i] = frag_ld(&Ah[wr * 64 + i * 16 + lm][koff]);
            al[i] = frag_ld(&Al[wr * 64 + i * 16 + lm][koff]);
        }
        #pragma unroll
        for (int j = 0; j < 4; ++j) {
            bf16x8 bh = frag_ld(&Bh[wc * 64 + j * 16 + lm][koff]);
            bf16x8 bl = frag_ld(&Bl[wc * 64 + j * 16 + lm][koff]);
            #pragma unroll
            for (int i = 0; i < 4; ++i) {
                acc[i][j] = __builtin_amdgcn_mfma_f32_16x16x32_bf16(ah[i], bh, acc[i][j], 0, 0, 0);
                acc[i][j] = __builtin_amdgcn_mfma_f32_16x16x32_bf16(al[i], bh, acc[i][j], 0, 0, 0);
                acc[i][j] = __builtin_amdgcn_mfma_f32_16x16x32_bf16(ah[i], bl, acc[i][j], 0, 0, 0);
            }
        }
        __syncthreads();
    }

    const int lg4 = (l >> 4) * 4;
    #pragma unroll
    for (int i = 0; i < 4; ++i)
        #pragma unroll
        for (int j = 0; j < 4; ++j) {
            int col  = bn + wc * 64 + j * 16 + lm;
            int row0 = bm + wr * 64 + i * 16 + lg4;
            float bb = bias[col];
            #pragma unroll
            for (int r = 0; r < 4; ++r)
                z[(size_t)(row0 + r) * ZDIM + col] = acc[i][j][r] + bb;
        }
}

// ---------------------------------------------------------------------------
// Gates: h,c <- lstm gates(z, c).  Keras order i,f,g,o.
// ---------------------------------------------------------------------------
__global__ __launch_bounds__(256) void gates_kernel(
    const float* __restrict__ z, const float* __restrict__ c_in,
    float* __restrict__ h_out, float* __restrict__ c_out)
{
    int idx = blockIdx.x * 256 + threadIdx.x;
    int s = idx >> 8, ch = idx & 255;
    const float* zr = z + (size_t)s * ZDIM;
    float zi = zr[ch], zf = zr[256 + ch], zg = zr[512 + ch], zo = zr[768 + ch];
    float cold = c_in[idx];
    float cn = sigm(zf) * cold + sigm(zi) * tanhf(zg);
    float hn = sigm(zo) * tanhf(cn);
    h_out[idx] = hn;
    c_out[idx] = cn;
}

// Step-1 closed form: q*=0, h=0, c=0 -> z = b (same for every structure)
__global__ void h1c1_kernel(const float* __restrict__ b, float* __restrict__ hc_rows) {
    int ch = threadIdx.x;
    float zi = b[ch], zg = b[512 + ch], zo = b[768 + ch];
    float cn = sigm(zi) * tanhf(zg);
    float hn = sigm(zo) * tanhf(cn);
    hc_rows[ch] = hn;
    hc_rows[256 + ch] = cn;
}

__global__ __launch_bounds__(256) void bcast_kernel(
    const float* __restrict__ hc_rows, float* __restrict__ h, float* __restrict__ c)
{
    int idx = blockIdx.x * 256 + threadIdx.x;
    int ch = idx & 255;
    h[idx] = hc_rows[ch];
    c[idx] = hc_rows[256 + ch];
}

// ---------------------------------------------------------------------------
// Attention: one block per segment, thread = channel, online softmax.
// ---------------------------------------------------------------------------
__global__ __launch_bounds__(256) void attn_kernel(
    const float* __restrict__ x, const float* __restrict__ h,
    const int* __restrict__ offs, float* __restrict__ qstar_out)
{
    const int s = blockIdx.x;
    const int ch = threadIdx.x;
    const float q = h[(size_t)s * UNITS + ch];
    const int a0 = offs[s], a1 = offs[s + 1];

    float m = -INFINITY, ssum = 0.0f, r = 0.0f;
    #pragma unroll 4
    for (int a = a0; a < a1; ++a) {
        float xv = x[(size_t)a * FEAT + ch];
        float e = xv * q;
        float mnew = fmaxf(m, e);
        float scale = __expf(m - mnew);
        float p = __expf(e - mnew);
        ssum = ssum * scale + p;
        r = r * scale + p * xv;
        m = mnew;
    }
    float rt = (a1 > a0) ? (r / ssum) : 0.0f;
    qstar_out[(size_t)s * QDIM + ch] = q;
    qstar_out[(size_t)s * QDIM + UNITS + ch] = rt;
}

// ---------------------------------------------------------------------------
extern "C" void kernel_launch(void* const* d_in, const int* in_sizes, int n_in,
                              void* d_out, int out_size, void* d_ws, size_t ws_size,
                              hipStream_t stream) {
    const float* field  = (const float*)d_in[0];
    const float* Wd     = (const float*)d_in[1];
    const float* bd     = (const float*)d_in[2];
    const float* Wk     = (const float*)d_in[3];
    const float* Wr     = (const float*)d_in[4];
    const float* b_lstm = (const float*)d_in[5];
    const int*   segids = (const int*)d_in[6];

    float* ws   = (float*)d_ws;
    float* x    = ws;                              // 33554432 f
    float* z    = x + (size_t)N_ATOMS * FEAT;      // 4194304 f
    float* qst  = z + (size_t)NSTRUCT * ZDIM;      // 2097152 f
    float* h    = qst + (size_t)NSTRUCT * QDIM;    // 1048576 f
    float* c    = h + (size_t)NSTRUCT * UNITS;     // 1048576 f
    float* hcr  = c + (size_t)NSTRUCT * UNITS;     // 512 f
    int*   offs = (int*)(hcr + 512);               // 4097 i

    // Pre-split weights live in the DEAD region of d_out (8 MB; we use 3.25 MB).
    // d_out is only written by the FINAL attn dispatch, which runs after the
    // last weight read. Rebuilt every launch (d_out is re-poisoned each call).
    unsigned short* wdt_h = (unsigned short*)d_out;        // [256][256]
    unsigned short* wdt_l = wdt_h + 256 * 256;
    unsigned short* wt_h  = wdt_l + 256 * 256;             // [1024][768]
    unsigned short* wt_l  = wt_h + 1024 * 768;

    seg_offs_kernel<<<(NSTRUCT + 1 + 255) / 256, 256, 0, stream>>>(segids, offs);
    prep_wd_kernel<<<256, 256, 0, stream>>>(Wd, wdt_h, wdt_l);
    prep_wlstm_kernel<<<3072, 256, 0, stream>>>(Wk, Wr, wt_h, wt_l);

    // x = field @ Wd + bd
    gemm_x_mfma<<<dim3(FEAT / 128, N_ATOMS / 128), 256, 0, stream>>>(
        field, wdt_h, wdt_l, bd, x);

    // step 1 (closed form LSTM from zero state)
    h1c1_kernel<<<1, 256, 0, stream>>>(b_lstm, hcr);
    bcast_kernel<<<NSTRUCT, 256, 0, stream>>>(hcr, h, c);
    attn_kernel<<<NSTRUCT, 256, 0, stream>>>(x, h, offs, qst);

    // steps 2, 3
    for (int step = 1; step < 3; ++step) {
        lstm_gemm_mfma<<<dim3(ZDIM / 128, NSTRUCT / 128), 256, 0, stream>>>(
            qst, h, wt_h, wt_l, b_lstm, z);
        gates_kernel<<<NSTRUCT, 256, 0, stream>>>(z, c, h, c);
        float* qdst = (step == 2) ? (float*)d_out : qst;
        attn_kernel<<<NSTRUCT, 256, 0, stream>>>(x, h, offs, qdst);
    }
}